// Round 1
// baseline (1018.297 us; speedup 1.0000x reference)
//
#include <hip/hip_runtime.h>
#include <hip/hip_bf16.h>
#include <math.h>

// Problem constants
#define Bb 32
#define Hh 56
#define Ww 56
#define Cc 128
#define HEAD 4
#define WS 7
#define SHIFT 3
#define Nn 49            // tokens per window
#define NWw 64           // windows per image
#define HD 32            // head dim
#define HID 512
#define TOK (Bb*Hh*Ww)   // 100352 total tokens
#define SCALEF 0.17677669529663687f  // 32^-0.5

// ---------------------------------------------------------------------------
// LayerNorm1 fused with cyclic shift + window partition gather.
// One 64-thread wave per output row t (window order). Row t sources from
// x[b][( wh*7+i+3 )%56][( ww*7+j+3 )%56].
// ---------------------------------------------------------------------------
__global__ __launch_bounds__(64) void ln1_gather(const float* __restrict__ x,
                                                 const float* __restrict__ g,
                                                 const float* __restrict__ b,
                                                 float* __restrict__ h) {
    int t = blockIdx.x;
    int lane = threadIdx.x;
    int bimg = t / (NWw * Nn);
    int wrow = t % (NWw * Nn);
    int wi = wrow / Nn, n = wrow % Nn;
    int wh = wi >> 3, ww = wi & 7;
    int i = n / 7, j = n % 7;
    int sr = (wh * 7 + i + SHIFT) % Hh;
    int scol = (ww * 7 + j + SHIFT) % Ww;
    const float* xr = x + ((size_t)bimg * (Hh * Ww) + sr * Ww + scol) * Cc;
    float2 v = ((const float2*)xr)[lane];
    float s = v.x + v.y;
    #pragma unroll
    for (int m = 32; m; m >>= 1) s += __shfl_xor(s, m, 64);
    float mean = s * (1.f / 128.f);
    float dx = v.x - mean, dy = v.y - mean;
    float vs = dx * dx + dy * dy;
    #pragma unroll
    for (int m = 32; m; m >>= 1) vs += __shfl_xor(vs, m, 64);
    float inv = rsqrtf(vs * (1.f / 128.f) + 1e-5f);
    float2 gg = ((const float2*)g)[lane];
    float2 bb = ((const float2*)b)[lane];
    float2 o;
    o.x = dx * inv * gg.x + bb.x;
    o.y = dy * inv * gg.y + bb.y;
    ((float2*)(h + (size_t)t * Cc))[lane] = o;
}

// ---------------------------------------------------------------------------
// QKV GEMM: (TOK x 128) @ (128 x 384) + bias. 16 rows per block, 128 threads,
// each thread owns one column in each of q/k/v (c, c+128, c+256).
// ---------------------------------------------------------------------------
#define QR 16
__global__ __launch_bounds__(128) void qkv_gemm(const float* __restrict__ h,
                                                const float* __restrict__ w,
                                                const float* __restrict__ bias,
                                                float* __restrict__ qkv) {
    __shared__ float As[QR * Cc];
    int t0 = blockIdx.x * QR;
    int c = threadIdx.x;
    #pragma unroll
    for (int r = 0; r < QR; ++r) As[r * Cc + c] = h[(size_t)(t0 + r) * Cc + c];
    __syncthreads();
    float acc0[QR], acc1[QR], acc2[QR];
    #pragma unroll
    for (int r = 0; r < QR; ++r) { acc0[r] = 0.f; acc1[r] = 0.f; acc2[r] = 0.f; }
    for (int k = 0; k < Cc; ++k) {
        float w0 = w[k * 384 + c];
        float w1 = w[k * 384 + 128 + c];
        float w2 = w[k * 384 + 256 + c];
        #pragma unroll
        for (int r = 0; r < QR; ++r) {
            float a = As[r * Cc + k];
            acc0[r] = fmaf(a, w0, acc0[r]);
            acc1[r] = fmaf(a, w1, acc1[r]);
            acc2[r] = fmaf(a, w2, acc2[r]);
        }
    }
    float b0 = bias[c], b1 = bias[128 + c], b2 = bias[256 + c];
    #pragma unroll
    for (int r = 0; r < QR; ++r) {
        size_t base = (size_t)(t0 + r) * 384;
        qkv[base + c] = acc0[r] + b0;
        qkv[base + 128 + c] = acc1[r] + b1;
        qkv[base + 256 + c] = acc2[r] + b2;
    }
}

// ---------------------------------------------------------------------------
// Windowed attention: one block per (window, head). q/k/v staged in LDS with
// stride 33 (kills stride-32 bank conflicts). Bias + shift-mask computed
// analytically. Softmax rows handled by 49 threads.
// ---------------------------------------------------------------------------
__global__ __launch_bounds__(256) void attn_kernel(const float* __restrict__ qkv,
                                                   const float* __restrict__ rpb,
                                                   float* __restrict__ o) {
    __shared__ float qs[Nn * 33];
    __shared__ float ks[Nn * 33];
    __shared__ float vs[Nn * 33];
    __shared__ float sc[Nn * Nn];
    int wid = blockIdx.x;
    int bw = wid >> 2, hd = wid & 3;
    int tid = threadIdx.x;
    for (int idx = tid; idx < Nn * HD; idx += 256) {
        int n = idx >> 5, d = idx & 31;
        size_t base = (size_t)(bw * Nn + n) * 384 + hd * HD + d;
        qs[n * 33 + d] = qkv[base] * SCALEF;
        ks[n * 33 + d] = qkv[base + 128];
        vs[n * 33 + d] = qkv[base + 256];
    }
    __syncthreads();
    int widx = bw & 63;
    int wh = widx >> 3, ww = widx & 7;
    for (int s = tid; s < Nn * Nn; s += 256) {
        int n = s / 49, mm = s % 49;
        int i1 = n / 7, j1 = n % 7, i2 = mm / 7, j2 = mm % 7;
        float dot = 0.f;
        #pragma unroll
        for (int d = 0; d < HD; ++d) dot = fmaf(qs[n * 33 + d], ks[mm * 33 + d], dot);
        float bias = rpb[((i1 - i2 + 6) * 13 + (j1 - j2 + 6)) * HEAD + hd];
        int rn = (wh < 7) ? 0 : (i1 < 4 ? 1 : 2);
        int cn = (ww < 7) ? 0 : (j1 < 4 ? 1 : 2);
        int rm = (wh < 7) ? 0 : (i2 < 4 ? 1 : 2);
        int cm = (ww < 7) ? 0 : (j2 < 4 ? 1 : 2);
        float mask = ((rn * 3 + cn) != (rm * 3 + cm)) ? -100.f : 0.f;
        sc[s] = dot + bias + mask;
    }
    __syncthreads();
    if (tid < Nn) {
        float mx = -1e30f;
        for (int mm = 0; mm < Nn; ++mm) mx = fmaxf(mx, sc[tid * 49 + mm]);
        float sum = 0.f;
        for (int mm = 0; mm < Nn; ++mm) {
            float e = __expf(sc[tid * 49 + mm] - mx);
            sc[tid * 49 + mm] = e;
            sum += e;
        }
        float inv = 1.f / sum;
        for (int mm = 0; mm < Nn; ++mm) sc[tid * 49 + mm] *= inv;
    }
    __syncthreads();
    for (int idx = tid; idx < Nn * HD; idx += 256) {
        int n = idx >> 5, d = idx & 31;
        float acc = 0.f;
        #pragma unroll
        for (int mm = 0; mm < Nn; ++mm) acc = fmaf(sc[n * 49 + mm], vs[mm * 33 + d], acc);
        o[(size_t)(bw * Nn + n) * Cc + hd * HD + d] = acc;
    }
}

// ---------------------------------------------------------------------------
// Proj GEMM fused with window-merge + reverse shift scatter + residual.
// Block iterates destination tokens; gathers source window rows.
// ---------------------------------------------------------------------------
#define PR 16
__global__ __launch_bounds__(128) void proj_scatter(const float* __restrict__ o,
                                                    const float* __restrict__ w,
                                                    const float* __restrict__ bias,
                                                    const float* __restrict__ x,
                                                    float* __restrict__ x1) {
    __shared__ float As[PR * Cc];
    int t0 = blockIdx.x * PR;
    int c = threadIdx.x;
    for (int r = 0; r < PR; ++r) {
        int t = t0 + r;
        int b = t / (Hh * Ww), pos = t % (Hh * Ww);
        int dr = pos / Ww, dc = pos % Ww;
        int rs = (dr + Hh - SHIFT) % Hh, cs = (dc + Ww - SHIFT) % Ww;
        int st = (b * NWw + (rs / 7) * 8 + (cs / 7)) * Nn + (rs % 7) * 7 + (cs % 7);
        As[r * Cc + c] = o[(size_t)st * Cc + c];
    }
    __syncthreads();
    float acc[PR];
    #pragma unroll
    for (int r = 0; r < PR; ++r) acc[r] = 0.f;
    for (int k = 0; k < Cc; ++k) {
        float wv = w[k * Cc + c];
        #pragma unroll
        for (int r = 0; r < PR; ++r) acc[r] = fmaf(As[r * Cc + k], wv, acc[r]);
    }
    float bb = bias[c];
    #pragma unroll
    for (int r = 0; r < PR; ++r) {
        size_t tt = (size_t)(t0 + r) * Cc + c;
        x1[tt] = x[tt] + bb + acc[r];
    }
}

// ---------------------------------------------------------------------------
// LayerNorm2 (plain, no gather)
// ---------------------------------------------------------------------------
__global__ __launch_bounds__(64) void ln2_kernel(const float* __restrict__ x1,
                                                 const float* __restrict__ g,
                                                 const float* __restrict__ b,
                                                 float* __restrict__ m) {
    int t = blockIdx.x;
    int lane = threadIdx.x;
    const float* xr = x1 + (size_t)t * Cc;
    float2 v = ((const float2*)xr)[lane];
    float s = v.x + v.y;
    #pragma unroll
    for (int mk = 32; mk; mk >>= 1) s += __shfl_xor(s, mk, 64);
    float mean = s * (1.f / 128.f);
    float dx = v.x - mean, dy = v.y - mean;
    float vs = dx * dx + dy * dy;
    #pragma unroll
    for (int mk = 32; mk; mk >>= 1) vs += __shfl_xor(vs, mk, 64);
    float inv = rsqrtf(vs * (1.f / 128.f) + 1e-5f);
    float2 gg = ((const float2*)g)[lane];
    float2 bb = ((const float2*)b)[lane];
    float2 o;
    o.x = dx * inv * gg.x + bb.x;
    o.y = dy * inv * gg.y + bb.y;
    ((float2*)(m + (size_t)t * Cc))[lane] = o;
}

// ---------------------------------------------------------------------------
// Fused MLP: fc1 + exact GELU + fc2 + residual. 8 rows/block, hidden in LDS.
// ---------------------------------------------------------------------------
#define MR 8
__global__ __launch_bounds__(256) void mlp_fused(const float* __restrict__ m,
                                                 const float* __restrict__ w1,
                                                 const float* __restrict__ b1,
                                                 const float* __restrict__ w2,
                                                 const float* __restrict__ b2,
                                                 const float* __restrict__ x1,
                                                 float* __restrict__ out) {
    __shared__ float ms[MR * Cc];
    __shared__ float hid[MR * HID];
    int t0 = blockIdx.x * MR;
    int tid = threadIdx.x;
    for (int idx = tid; idx < MR * Cc; idx += 256) ms[idx] = m[(size_t)t0 * Cc + idx];
    __syncthreads();
    // stage 1: fc1 + gelu
    float acc0[MR], acc1[MR];
    #pragma unroll
    for (int r = 0; r < MR; ++r) { acc0[r] = 0.f; acc1[r] = 0.f; }
    int c = tid;  // 0..255
    for (int k = 0; k < Cc; ++k) {
        float wa = w1[k * HID + c];
        float wb = w1[k * HID + c + 256];
        #pragma unroll
        for (int r = 0; r < MR; ++r) {
            float a = ms[r * Cc + k];
            acc0[r] = fmaf(a, wa, acc0[r]);
            acc1[r] = fmaf(a, wb, acc1[r]);
        }
    }
    float bb0 = b1[c], bb1 = b1[c + 256];
    #pragma unroll
    for (int r = 0; r < MR; ++r) {
        float h0 = acc0[r] + bb0;
        float h1 = acc1[r] + bb1;
        hid[r * HID + c]       = 0.5f * h0 * (1.f + erff(h0 * 0.70710678118f));
        hid[r * HID + c + 256] = 0.5f * h1 * (1.f + erff(h1 * 0.70710678118f));
    }
    __syncthreads();
    // stage 2: fc2 + residual
    int c2 = tid & 127;
    int half = tid >> 7;
    float acc2[MR / 2];
    #pragma unroll
    for (int r = 0; r < MR / 2; ++r) acc2[r] = 0.f;
    for (int k = 0; k < HID; ++k) {
        float wv = w2[k * Cc + c2];
        #pragma unroll
        for (int r = 0; r < MR / 2; ++r)
            acc2[r] = fmaf(hid[(half * (MR / 2) + r) * HID + k], wv, acc2[r]);
    }
    float bo = b2[c2];
    #pragma unroll
    for (int r = 0; r < MR / 2; ++r) {
        size_t tt = (size_t)(t0 + half * (MR / 2) + r) * Cc + c2;
        out[tt] = x1[tt] + bo + acc2[r];
    }
}

// ---------------------------------------------------------------------------
extern "C" void kernel_launch(void* const* d_in, const int* in_sizes, int n_in,
                              void* d_out, int out_size, void* d_ws, size_t ws_size,
                              hipStream_t stream) {
    const float* x     = (const float*)d_in[0];
    const float* n1g   = (const float*)d_in[1];
    const float* n1b   = (const float*)d_in[2];
    const float* qkvw  = (const float*)d_in[3];
    const float* qkvb  = (const float*)d_in[4];
    const float* projw = (const float*)d_in[5];
    const float* projb = (const float*)d_in[6];
    const float* rpb   = (const float*)d_in[7];
    const float* n2g   = (const float*)d_in[8];
    const float* n2b   = (const float*)d_in[9];
    const float* fc1w  = (const float*)d_in[10];
    const float* fc1b  = (const float*)d_in[11];
    const float* fc2w  = (const float*)d_in[12];
    const float* fc2b  = (const float*)d_in[13];
    float* out = (float*)d_out;

    // workspace layout (floats):
    //   region0 [0, 12845056)           : h -> o -> m   (51.4 MB)
    //   region1 [12845056, 51380224)    : qkv -> x1(+spare) (154.1 MB)
    float* h   = (float*)d_ws;
    float* qkv = h + (size_t)TOK * Cc;       // 12,845,056 floats in
    float* o   = h;                          // reuse after qkv_gemm
    float* x1  = qkv;                        // reuse after attention
    float* m   = h;                          // reuse after proj

    ln1_gather<<<TOK, 64, 0, stream>>>(x, n1g, n1b, h);
    qkv_gemm<<<TOK / QR, 128, 0, stream>>>(h, qkvw, qkvb, qkv);
    attn_kernel<<<(TOK / Nn) * HEAD, 256, 0, stream>>>(qkv, rpb, o);
    proj_scatter<<<TOK / PR, 128, 0, stream>>>(o, projw, projb, x, x1);
    ln2_kernel<<<TOK, 64, 0, stream>>>(x1, n2g, n2b, m);
    mlp_fused<<<TOK / MR, 256, 0, stream>>>(m, fc1w, fc1b, fc2w, fc2b, x1, out);
}

// Round 2
// 719.999 us; speedup vs baseline: 1.4143x; 1.4143x over previous
//
#include <hip/hip_runtime.h>
#include <hip/hip_bf16.h>
#include <math.h>

#define Bb 32
#define Hh 56
#define Ww 56
#define Cc 128
#define HEAD 4
#define WS 7
#define SHIFT 3
#define Nn 49
#define NWw 64
#define HD 32
#define HID 512
#define TOK (Bb*Hh*Ww)
#define SCALEF 0.17677669529663687f

typedef short short8 __attribute__((ext_vector_type(8)));
typedef float f32x4 __attribute__((ext_vector_type(4)));

__device__ __forceinline__ short f2bf(float f) {
    union { float f; unsigned u; } c; c.f = f;
    unsigned r = (c.u + 0x7fff + ((c.u >> 16) & 1)) >> 16;
    return (short)r;
}
__device__ __forceinline__ float bf2f(short s) {
    union { unsigned u; float f; } c; c.u = ((unsigned)(unsigned short)s) << 16;
    return c.f;
}

// ---------------------------------------------------------------------------
// Weight convert + transpose: in fp32 [K x N] -> out bf16 [N x K]
// ---------------------------------------------------------------------------
__global__ void conv_t(const float* __restrict__ in, short* __restrict__ out,
                       int K, int N) {
    int idx = blockIdx.x * 256 + threadIdx.x;
    if (idx >= K * N) return;
    int k = idx / N, n = idx % N;
    out[(size_t)n * K + k] = f2bf(in[idx]);
}

// ---------------------------------------------------------------------------
// LN1 + cyclic shift + window partition gather -> bf16 h (window-row order)
// ---------------------------------------------------------------------------
__global__ __launch_bounds__(64) void ln1_gather(const float* __restrict__ x,
                                                 const float* __restrict__ g,
                                                 const float* __restrict__ b,
                                                 short* __restrict__ h) {
    int t = blockIdx.x;
    int lane = threadIdx.x;
    int bimg = t / (NWw * Nn);
    int wrow = t % (NWw * Nn);
    int wi = wrow / Nn, n = wrow % Nn;
    int wh = wi >> 3, ww = wi & 7;
    int i = n / 7, j = n % 7;
    int sr = (wh * 7 + i + SHIFT) % Hh;
    int scol = (ww * 7 + j + SHIFT) % Ww;
    const float* xr = x + ((size_t)bimg * (Hh * Ww) + sr * Ww + scol) * Cc;
    float2 v = ((const float2*)xr)[lane];
    float s = v.x + v.y;
    #pragma unroll
    for (int m = 32; m; m >>= 1) s += __shfl_xor(s, m, 64);
    float mean = s * (1.f / 128.f);
    float dx = v.x - mean, dy = v.y - mean;
    float vs = dx * dx + dy * dy;
    #pragma unroll
    for (int m = 32; m; m >>= 1) vs += __shfl_xor(vs, m, 64);
    float inv = rsqrtf(vs * (1.f / 128.f) + 1e-5f);
    float2 gg = ((const float2*)g)[lane];
    float2 bb = ((const float2*)b)[lane];
    unsigned p0 = (unsigned)(unsigned short)f2bf(dx * inv * gg.x + bb.x);
    unsigned p1 = (unsigned)(unsigned short)f2bf(dy * inv * gg.y + bb.y);
    ((unsigned*)(h + (size_t)t * Cc))[lane] = p0 | (p1 << 16);
}

// ---------------------------------------------------------------------------
// QKV GEMM via MFMA: h bf16 [TOK x 128] @ wt bf16 [384 x 128]^T + bias
// -> qkv bf16 [TOK x 384]. 64 rows/block, wave w = 16 rows, 3 col chunks.
// ---------------------------------------------------------------------------
__global__ __launch_bounds__(256) void qkv_mfma(const short* __restrict__ h,
                                                const short* __restrict__ wt,
                                                const float* __restrict__ bias,
                                                short* __restrict__ qkv) {
    int wave = threadIdx.x >> 6, lane = threadIdx.x & 63;
    int row16 = lane & 15, quad = lane >> 4;
    size_t r0 = (size_t)blockIdx.x * 64 + wave * 16;
    short8 afr[4];
    #pragma unroll
    for (int k = 0; k < 4; ++k)
        afr[k] = *(const short8*)(h + (r0 + row16) * Cc + k * 32 + quad * 8);
    for (int ch = 0; ch < 3; ++ch) {
        f32x4 acc[8];
        #pragma unroll
        for (int n = 0; n < 8; ++n) acc[n] = (f32x4)(0.f);
        #pragma unroll
        for (int k = 0; k < 4; ++k) {
            #pragma unroll
            for (int n = 0; n < 8; ++n) {
                short8 bfr = *(const short8*)(wt + (size_t)(ch * 128 + n * 16 + row16) * Cc + k * 32 + quad * 8);
                acc[n] = __builtin_amdgcn_mfma_f32_16x16x32_bf16(afr[k], bfr, acc[n], 0, 0, 0);
            }
        }
        #pragma unroll
        for (int n = 0; n < 8; ++n) {
            #pragma unroll
            for (int r = 0; r < 4; ++r) {
                int row = quad * 4 + r;
                int col = ch * 128 + n * 16 + row16;
                qkv[(r0 + row) * 384 + col] = f2bf(acc[n][r] + bias[col]);
            }
        }
    }
}

// ---------------------------------------------------------------------------
// Windowed attention (fp32 VALU compute on bf16 inputs), writes o bf16.
// ---------------------------------------------------------------------------
__global__ __launch_bounds__(256) void attn_kernel(const short* __restrict__ qkv,
                                                   const float* __restrict__ rpb,
                                                   short* __restrict__ o) {
    __shared__ float qs[Nn * 33];
    __shared__ float ks[Nn * 33];
    __shared__ float vs[Nn * 33];
    __shared__ float sc[Nn * Nn];
    int wid = blockIdx.x;
    int bw = wid >> 2, hd = wid & 3;
    int tid = threadIdx.x;
    for (int idx = tid; idx < Nn * HD; idx += 256) {
        int n = idx >> 5, d = idx & 31;
        size_t base = (size_t)(bw * Nn + n) * 384 + hd * HD + d;
        qs[n * 33 + d] = bf2f(qkv[base]) * SCALEF;
        ks[n * 33 + d] = bf2f(qkv[base + 128]);
        vs[n * 33 + d] = bf2f(qkv[base + 256]);
    }
    __syncthreads();
    int widx = bw & 63;
    int wh = widx >> 3, ww = widx & 7;
    for (int s = tid; s < Nn * Nn; s += 256) {
        int n = s / 49, mm = s % 49;
        int i1 = n / 7, j1 = n % 7, i2 = mm / 7, j2 = mm % 7;
        float dot = 0.f;
        #pragma unroll
        for (int d = 0; d < HD; ++d) dot = fmaf(qs[n * 33 + d], ks[mm * 33 + d], dot);
        float bias = rpb[((i1 - i2 + 6) * 13 + (j1 - j2 + 6)) * HEAD + hd];
        int rn = (wh < 7) ? 0 : (i1 < 4 ? 1 : 2);
        int cn = (ww < 7) ? 0 : (j1 < 4 ? 1 : 2);
        int rm = (wh < 7) ? 0 : (i2 < 4 ? 1 : 2);
        int cm = (ww < 7) ? 0 : (j2 < 4 ? 1 : 2);
        float mask = ((rn * 3 + cn) != (rm * 3 + cm)) ? -100.f : 0.f;
        sc[s] = dot + bias + mask;
    }
    __syncthreads();
    if (tid < Nn) {
        float mx = -1e30f;
        for (int mm = 0; mm < Nn; ++mm) mx = fmaxf(mx, sc[tid * 49 + mm]);
        float sum = 0.f;
        for (int mm = 0; mm < Nn; ++mm) {
            float e = __expf(sc[tid * 49 + mm] - mx);
            sc[tid * 49 + mm] = e;
            sum += e;
        }
        float inv = 1.f / sum;
        for (int mm = 0; mm < Nn; ++mm) sc[tid * 49 + mm] *= inv;
    }
    __syncthreads();
    for (int idx = tid; idx < Nn * HD; idx += 256) {
        int n = idx >> 5, d = idx & 31;
        float acc = 0.f;
        #pragma unroll
        for (int mm = 0; mm < Nn; ++mm) acc = fmaf(sc[n * 49 + mm], vs[mm * 33 + d], acc);
        o[(size_t)(bw * Nn + n) * Cc + hd * HD + d] = f2bf(acc);
    }
}

// ---------------------------------------------------------------------------
// Proj GEMM via MFMA + window-merge + reverse-shift scatter + residual.
// o bf16 [TOK x 128] (window order) @ wt bf16 [128 x 128] -> x1 fp32 (token order)
// ---------------------------------------------------------------------------
__global__ __launch_bounds__(256) void proj_mfma(const short* __restrict__ o,
                                                 const short* __restrict__ wt,
                                                 const float* __restrict__ bias,
                                                 const float* __restrict__ x,
                                                 float* __restrict__ x1) {
    __shared__ int dest[64];
    int tid = threadIdx.x;
    int wave = tid >> 6, lane = tid & 63;
    int row16 = lane & 15, quad = lane >> 4;
    size_t s0 = (size_t)blockIdx.x * 64;
    if (tid < 64) {
        int st = (int)s0 + tid;
        int bimg = st / (NWw * Nn);
        int rem = st % (NWw * Nn);
        int wi = rem / Nn, n = rem % Nn;
        int wh = wi >> 3, ww = wi & 7;
        int i = n / 7, j = n % 7;
        int dr = (wh * 7 + i + SHIFT) % Hh;
        int dc = (ww * 7 + j + SHIFT) % Ww;
        dest[tid] = bimg * (Hh * Ww) + dr * Ww + dc;
    }
    __syncthreads();
    size_t r0 = s0 + wave * 16;
    short8 afr[4];
    #pragma unroll
    for (int k = 0; k < 4; ++k)
        afr[k] = *(const short8*)(o + (r0 + row16) * Cc + k * 32 + quad * 8);
    f32x4 acc[8];
    #pragma unroll
    for (int n = 0; n < 8; ++n) acc[n] = (f32x4)(0.f);
    #pragma unroll
    for (int k = 0; k < 4; ++k) {
        #pragma unroll
        for (int n = 0; n < 8; ++n) {
            short8 bfr = *(const short8*)(wt + (size_t)(n * 16 + row16) * Cc + k * 32 + quad * 8);
            acc[n] = __builtin_amdgcn_mfma_f32_16x16x32_bf16(afr[k], bfr, acc[n], 0, 0, 0);
        }
    }
    #pragma unroll
    for (int n = 0; n < 8; ++n) {
        #pragma unroll
        for (int r = 0; r < 4; ++r) {
            int lrow = wave * 16 + quad * 4 + r;
            int col = n * 16 + row16;
            size_t idx = (size_t)dest[lrow] * Cc + col;
            x1[idx] = x[idx] + bias[col] + acc[n][r];
        }
    }
}

// ---------------------------------------------------------------------------
// LN2: x1 fp32 -> m bf16
// ---------------------------------------------------------------------------
__global__ __launch_bounds__(64) void ln2_kernel(const float* __restrict__ x1,
                                                 const float* __restrict__ g,
                                                 const float* __restrict__ b,
                                                 short* __restrict__ m) {
    int t = blockIdx.x;
    int lane = threadIdx.x;
    const float* xr = x1 + (size_t)t * Cc;
    float2 v = ((const float2*)xr)[lane];
    float s = v.x + v.y;
    #pragma unroll
    for (int mk = 32; mk; mk >>= 1) s += __shfl_xor(s, mk, 64);
    float mean = s * (1.f / 128.f);
    float dx = v.x - mean, dy = v.y - mean;
    float vs = dx * dx + dy * dy;
    #pragma unroll
    for (int mk = 32; mk; mk >>= 1) vs += __shfl_xor(vs, mk, 64);
    float inv = rsqrtf(vs * (1.f / 128.f) + 1e-5f);
    float2 gg = ((const float2*)g)[lane];
    float2 bb = ((const float2*)b)[lane];
    unsigned p0 = (unsigned)(unsigned short)f2bf(dx * inv * gg.x + bb.x);
    unsigned p1 = (unsigned)(unsigned short)f2bf(dy * inv * gg.y + bb.y);
    ((unsigned*)(m + (size_t)t * Cc))[lane] = p0 | (p1 << 16);
}

// ---------------------------------------------------------------------------
// Fused MLP via MFMA: m bf16 @ W1 -> GELU -> @ W2 + x1 -> out fp32.
// 64 rows/block, each wave fully independent on its 16 rows.
// FC1 done in 4 chunks of 128 hid cols; H chunk round-trips LDS (layout
// transform C-layout -> A-layout); FC2 accumulates progressively.
// ---------------------------------------------------------------------------
__global__ __launch_bounds__(256) void mlp_mfma(const short* __restrict__ m,
                                                const short* __restrict__ w1t,
                                                const float* __restrict__ b1,
                                                const short* __restrict__ w2t,
                                                const float* __restrict__ b2,
                                                const float* __restrict__ x1,
                                                float* __restrict__ out) {
    __shared__ short Hs[4][16 * 136];
    int wave = threadIdx.x >> 6, lane = threadIdx.x & 63;
    int row16 = lane & 15, quad = lane >> 4;
    size_t r0 = (size_t)blockIdx.x * 64 + wave * 16;
    short* Hw = &Hs[wave][0];
    short8 afr[4];
    #pragma unroll
    for (int k = 0; k < 4; ++k)
        afr[k] = *(const short8*)(m + (r0 + row16) * Cc + k * 32 + quad * 8);
    f32x4 acc2[8];
    #pragma unroll
    for (int n = 0; n < 8; ++n) acc2[n] = (f32x4)(0.f);
    for (int ch = 0; ch < 4; ++ch) {
        f32x4 acc1[8];
        #pragma unroll
        for (int n = 0; n < 8; ++n) acc1[n] = (f32x4)(0.f);
        #pragma unroll
        for (int k = 0; k < 4; ++k) {
            #pragma unroll
            for (int n = 0; n < 8; ++n) {
                short8 bfr = *(const short8*)(w1t + (size_t)(ch * 128 + n * 16 + row16) * Cc + k * 32 + quad * 8);
                acc1[n] = __builtin_amdgcn_mfma_f32_16x16x32_bf16(afr[k], bfr, acc1[n], 0, 0, 0);
            }
        }
        // GELU -> H chunk (bf16) in per-wave LDS
        #pragma unroll
        for (int n = 0; n < 8; ++n) {
            #pragma unroll
            for (int r = 0; r < 4; ++r) {
                int row = quad * 4 + r;
                int col = n * 16 + row16;
                float hv = acc1[n][r] + b1[ch * 128 + col];
                hv = 0.5f * hv * (1.f + erff(hv * 0.70710678118f));
                Hw[row * 136 + col] = f2bf(hv);
            }
        }
        __syncthreads();
        // FC2 partial over this k-chunk of 128
        #pragma unroll
        for (int k = 0; k < 4; ++k) {
            short8 a = *(const short8*)(Hw + row16 * 136 + k * 32 + quad * 8);
            #pragma unroll
            for (int n = 0; n < 8; ++n) {
                short8 bfr = *(const short8*)(w2t + (size_t)(n * 16 + row16) * HID + ch * 128 + k * 32 + quad * 8);
                acc2[n] = __builtin_amdgcn_mfma_f32_16x16x32_bf16(a, bfr, acc2[n], 0, 0, 0);
            }
        }
        __syncthreads();
    }
    #pragma unroll
    for (int n = 0; n < 8; ++n) {
        #pragma unroll
        for (int r = 0; r < 4; ++r) {
            int row = quad * 4 + r;
            int col = n * 16 + row16;
            size_t idx = (r0 + row) * Cc + col;
            out[idx] = x1[idx] + b2[col] + acc2[n][r];
        }
    }
}

// ---------------------------------------------------------------------------
extern "C" void kernel_launch(void* const* d_in, const int* in_sizes, int n_in,
                              void* d_out, int out_size, void* d_ws, size_t ws_size,
                              hipStream_t stream) {
    const float* x     = (const float*)d_in[0];
    const float* n1g   = (const float*)d_in[1];
    const float* n1b   = (const float*)d_in[2];
    const float* qkvw  = (const float*)d_in[3];
    const float* qkvb  = (const float*)d_in[4];
    const float* projw = (const float*)d_in[5];
    const float* projb = (const float*)d_in[6];
    const float* rpb   = (const float*)d_in[7];
    const float* n2g   = (const float*)d_in[8];
    const float* n2b   = (const float*)d_in[9];
    const float* fc1w  = (const float*)d_in[10];
    const float* fc1b  = (const float*)d_in[11];
    const float* fc2w  = (const float*)d_in[12];
    const float* fc2b  = (const float*)d_in[13];
    float* out = (float*)d_out;

    // workspace layout (bytes), lifetimes overlapped:
    //   [0)              qkv bf16   77,070,336
    //   [qkv)            x1  fp32   51,380,224
    //   [x1)             h/m bf16   25,690,112   (h dies after qkv_mfma; m reuses)
    //   [h)              o   bf16   25,690,112
    //   [o)              weights bf16 ~0.4 MB
    char* ws = (char*)d_ws;
    short* qkv   = (short*)ws;
    float* x1    = (float*)(ws + 77070336);
    short* h     = (short*)(ws + 77070336 + 51380224);
    short* m     = h;
    short* o     = (short*)(ws + 77070336 + 51380224 + 25690112);
    short* qkvwT = (short*)(ws + 77070336 + 51380224 + 2 * 25690112);
    short* projwT= qkvwT + 384 * 128;
    short* fc1wT = projwT + 128 * 128;
    short* fc2wT = fc1wT + 512 * 128;

    conv_t<<<(128 * 384 + 255) / 256, 256, 0, stream>>>(qkvw, qkvwT, 128, 384);
    conv_t<<<(128 * 128 + 255) / 256, 256, 0, stream>>>(projw, projwT, 128, 128);
    conv_t<<<(128 * 512 + 255) / 256, 256, 0, stream>>>(fc1w, fc1wT, 128, 512);
    conv_t<<<(512 * 128 + 255) / 256, 256, 0, stream>>>(fc2w, fc2wT, 512, 128);

    ln1_gather<<<TOK, 64, 0, stream>>>(x, n1g, n1b, h);
    qkv_mfma<<<TOK / 64, 256, 0, stream>>>(h, qkvwT, qkvb, qkv);
    attn_kernel<<<(TOK / Nn) * HEAD, 256, 0, stream>>>(qkv, rpb, o);
    proj_mfma<<<TOK / 64, 256, 0, stream>>>(o, projwT, projb, x, x1);
    ln2_kernel<<<TOK, 64, 0, stream>>>(x1, n2g, n2b, m);
    mlp_mfma<<<TOK / 64, 256, 0, stream>>>(m, fc1wT, fc1b, fc2wT, fc2b, x1, out);
}

// Round 3
// 460.855 us; speedup vs baseline: 2.2096x; 1.5623x over previous
//
#include <hip/hip_runtime.h>
#include <hip/hip_bf16.h>
#include <math.h>

#define Bb 32
#define Hh 56
#define Ww 56
#define Cc 128
#define HEAD 4
#define WS 7
#define SHIFT 3
#define Nn 49
#define NWw 64
#define HD 32
#define HID 512
#define TOK (Bb*Hh*Ww)
#define SCALEF 0.17677669529663687f

typedef short short8 __attribute__((ext_vector_type(8)));
typedef float f32x4 __attribute__((ext_vector_type(4)));

__device__ __forceinline__ short f2bf(float f) {
    union { float f; unsigned u; } c; c.f = f;
    unsigned r = (c.u + 0x7fff + ((c.u >> 16) & 1)) >> 16;
    return (short)r;
}
__device__ __forceinline__ float gelu_fast(float x) {
    float x3 = x * x * x;
    float y = 0.7978845608f * (x + 0.044715f * x3);
    float e = __expf(2.f * y);
    float t = 1.f - 2.f / (e + 1.f);
    return 0.5f * x * (1.f + t);
}
#define LDS_FENCE() asm volatile("s_waitcnt lgkmcnt(0)" ::: "memory")

// ---------------------------------------------------------------------------
// Weight convert + transpose: fp32 [K x N] -> bf16 [N x K]
// ---------------------------------------------------------------------------
__global__ void conv_t(const float* __restrict__ in, short* __restrict__ out,
                       int K, int N) {
    int idx = blockIdx.x * 256 + threadIdx.x;
    if (idx >= K * N) return;
    int k = idx / N, n = idx % N;
    out[(size_t)n * K + k] = f2bf(in[idx]);
}

// ---------------------------------------------------------------------------
// Bias+mask table: [cls(4)][head(4)][row(64)][col(64)] fp32.
// Pad entries (row>=49 or col>=49) = -1e30 (doubles as the col mask).
// cls bit1 = row-masked window (wh==7), bit0 = col-masked (ww==7).
// ---------------------------------------------------------------------------
__global__ void build_table(const float* __restrict__ rpb, float* __restrict__ table) {
    int idx = blockIdx.x * 256 + threadIdx.x;
    if (idx >= 16 * 4096) return;
    int cell = idx & 4095, ch = idx >> 12;
    int cls = ch >> 2, hd = ch & 3;
    int row = cell >> 6, col = cell & 63;
    float v;
    if (row >= Nn || col >= Nn) v = -1e30f;
    else {
        int i1 = row / 7, j1 = row % 7, i2 = col / 7, j2 = col % 7;
        float bias = rpb[((i1 - i2 + 6) * 13 + (j1 - j2 + 6)) * HEAD + hd];
        int bh = cls >> 1, bw = cls & 1;
        int rn = bh ? (i1 < 4 ? 1 : 2) : 0;
        int cn = bw ? (j1 < 4 ? 1 : 2) : 0;
        int rm = bh ? (i2 < 4 ? 1 : 2) : 0;
        int cm = bw ? (j2 < 4 ? 1 : 2) : 0;
        v = bias + (((rn * 3 + cn) != (rm * 3 + cm)) ? -100.f : 0.f);
    }
    table[idx] = v;
}

// ---------------------------------------------------------------------------
// LN1 + cyclic shift + window partition gather -> bf16 h. 4 rows/block.
// ---------------------------------------------------------------------------
__global__ __launch_bounds__(256) void ln1_gather(const float* __restrict__ x,
                                                  const float* __restrict__ g,
                                                  const float* __restrict__ b,
                                                  short* __restrict__ h) {
    int wave = threadIdx.x >> 6, lane = threadIdx.x & 63;
    int t = blockIdx.x * 4 + wave;
    int bimg = t / (NWw * Nn);
    int wrow = t % (NWw * Nn);
    int wi = wrow / Nn, n = wrow % Nn;
    int wh = wi >> 3, ww = wi & 7;
    int i = n / 7, j = n % 7;
    int sr = (wh * 7 + i + SHIFT) % Hh;
    int scol = (ww * 7 + j + SHIFT) % Ww;
    const float* xr = x + ((size_t)bimg * (Hh * Ww) + sr * Ww + scol) * Cc;
    float2 v = ((const float2*)xr)[lane];
    float s = v.x + v.y;
    #pragma unroll
    for (int m = 32; m; m >>= 1) s += __shfl_xor(s, m, 64);
    float mean = s * (1.f / 128.f);
    float dx = v.x - mean, dy = v.y - mean;
    float vs = dx * dx + dy * dy;
    #pragma unroll
    for (int m = 32; m; m >>= 1) vs += __shfl_xor(vs, m, 64);
    float inv = rsqrtf(vs * (1.f / 128.f) + 1e-5f);
    float2 gg = ((const float2*)g)[lane];
    float2 bb = ((const float2*)b)[lane];
    unsigned p0 = (unsigned)(unsigned short)f2bf(dx * inv * gg.x + bb.x);
    unsigned p1 = (unsigned)(unsigned short)f2bf(dy * inv * gg.y + bb.y);
    ((unsigned*)(h + (size_t)t * Cc))[lane] = p0 | (p1 << 16);
}

// ---------------------------------------------------------------------------
// QKV GEMM, 32 rows/wave (2 row-tiles -> 2x B reuse). Q pre-scaled by SCALEF.
// ---------------------------------------------------------------------------
__global__ __launch_bounds__(256) void qkv_mfma(const short* __restrict__ h,
                                                const short* __restrict__ wt,
                                                const float* __restrict__ bias,
                                                short* __restrict__ qkv) {
    int wave = threadIdx.x >> 6, lane = threadIdx.x & 63;
    int row16 = lane & 15, quad = lane >> 4;
    size_t r0 = (size_t)blockIdx.x * 128 + wave * 32;
    short8 afr[2][4];
    #pragma unroll
    for (int rt = 0; rt < 2; ++rt)
        #pragma unroll
        for (int k = 0; k < 4; ++k)
            afr[rt][k] = *(const short8*)(h + (r0 + rt * 16 + row16) * Cc + k * 32 + quad * 8);
    for (int ch = 0; ch < 3; ++ch) {
        f32x4 acc[2][8];
        #pragma unroll
        for (int rt = 0; rt < 2; ++rt)
            #pragma unroll
            for (int n = 0; n < 8; ++n) acc[rt][n] = (f32x4)(0.f);
        #pragma unroll
        for (int k = 0; k < 4; ++k) {
            #pragma unroll
            for (int n = 0; n < 8; ++n) {
                short8 bfr = *(const short8*)(wt + (size_t)(ch * 128 + n * 16 + row16) * Cc + k * 32 + quad * 8);
                acc[0][n] = __builtin_amdgcn_mfma_f32_16x16x32_bf16(afr[0][k], bfr, acc[0][n], 0, 0, 0);
                acc[1][n] = __builtin_amdgcn_mfma_f32_16x16x32_bf16(afr[1][k], bfr, acc[1][n], 0, 0, 0);
            }
        }
        #pragma unroll
        for (int rt = 0; rt < 2; ++rt)
            #pragma unroll
            for (int n = 0; n < 8; ++n) {
                int col = ch * 128 + n * 16 + row16;
                float bv = bias[col];
                #pragma unroll
                for (int r = 0; r < 4; ++r) {
                    float val = acc[rt][n][r] + bv;
                    if (ch == 0) val *= SCALEF;
                    qkv[(r0 + rt * 16 + quad * 4 + r) * 384 + col] = f2bf(val);
                }
            }
    }
}

// ---------------------------------------------------------------------------
// MFMA attention: one wave per (window, head). 8192 units, 4 waves/block.
//   QK^T: A=Q, B=K fragments straight from global (layouts match).
//   softmax on C-layout scores, bias+mask from table (pad = -1e30 masks cols).
//   P -> LDS (C->A transform); V staged transposed -> b128 B fragments.
// ---------------------------------------------------------------------------
__global__ __launch_bounds__(256) void attn_mfma(const short* __restrict__ qkv,
                                                 const float* __restrict__ table,
                                                 short* __restrict__ o) {
    __shared__ short Pbuf[4][64 * 72];
    __shared__ short Vbuf[4][32 * 72];
    int wave = threadIdx.x >> 6, lane = threadIdx.x & 63;
    int row16 = lane & 15, quad = lane >> 4;
    int unit = blockIdx.x * 4 + wave;
    int bw = unit >> 2, hd = unit & 3;
    int widx = bw & 63, wh = widx >> 3, ww = widx & 7;
    int cls = ((wh == 7) ? 2 : 0) | ((ww == 7) ? 1 : 0);
    const float* tb = table + ((size_t)(cls * 4 + hd)) * 4096;
    short* P = &Pbuf[wave][0];
    short* vt = &Vbuf[wave][0];
    const short* base = qkv + (size_t)bw * Nn * 384 + hd * HD;

    // stage V transposed: vt[d][t], zeros for t>=49
    {
        int t = lane;
        if (t < Nn) {
            const short* vrow = base + (size_t)t * 384 + 256;
            #pragma unroll
            for (int d = 0; d < HD; d += 2) {
                unsigned pr = *(const unsigned*)(vrow + d);
                vt[d * 72 + t] = (short)(pr & 0xffff);
                vt[(d + 1) * 72 + t] = (short)(pr >> 16);
            }
        } else {
            #pragma unroll
            for (int d = 0; d < HD; ++d) vt[d * 72 + t] = 0;
        }
    }

    // QK^T fragments (zero-padded beyond 49 rows)
    short8 qa[4], kb[4];
    #pragma unroll
    for (int mt = 0; mt < 4; ++mt) {
        int r = mt * 16 + row16;
        if (r < Nn) {
            qa[mt] = *(const short8*)(base + (size_t)r * 384 + quad * 8);
            kb[mt] = *(const short8*)(base + (size_t)r * 384 + 128 + quad * 8);
        } else {
            qa[mt] = (short8)(short)0;
            kb[mt] = (short8)(short)0;
        }
    }
    f32x4 s[4][4];
    #pragma unroll
    for (int mt = 0; mt < 4; ++mt)
        #pragma unroll
        for (int nt = 0; nt < 4; ++nt)
            s[mt][nt] = __builtin_amdgcn_mfma_f32_16x16x32_bf16(qa[mt], kb[nt], (f32x4)(0.f), 0, 0, 0);

    // bias+mask, softmax (rows spread over nt in-lane and row16 across lanes)
    #pragma unroll
    for (int mt = 0; mt < 4; ++mt) {
        #pragma unroll
        for (int r = 0; r < 4; ++r) {
            int row = mt * 16 + quad * 4 + r;
            float mx = -1e30f;
            #pragma unroll
            for (int nt = 0; nt < 4; ++nt) {
                s[mt][nt][r] += tb[row * 64 + nt * 16 + row16];
                mx = fmaxf(mx, s[mt][nt][r]);
            }
            #pragma unroll
            for (int m = 1; m < 16; m <<= 1) mx = fmaxf(mx, __shfl_xor(mx, m, 64));
            float sm = 0.f;
            #pragma unroll
            for (int nt = 0; nt < 4; ++nt) {
                float e = __expf(s[mt][nt][r] - mx);
                s[mt][nt][r] = e;
                sm += e;
            }
            #pragma unroll
            for (int m = 1; m < 16; m <<= 1) sm += __shfl_xor(sm, m, 64);
            float inv = 1.f / sm;
            #pragma unroll
            for (int nt = 0; nt < 4; ++nt)
                P[row * 72 + nt * 16 + row16] = f2bf(s[mt][nt][r] * inv);
        }
    }
    LDS_FENCE();

    // PV: A=P (from LDS), B=V^T rows (b128 from LDS)
    f32x4 oacc[4][2];
    #pragma unroll
    for (int mt = 0; mt < 4; ++mt)
        #pragma unroll
        for (int nt = 0; nt < 2; ++nt) oacc[mt][nt] = (f32x4)(0.f);
    #pragma unroll
    for (int kt = 0; kt < 2; ++kt) {
        short8 pa[4], vb[2];
        #pragma unroll
        for (int mt = 0; mt < 4; ++mt)
            pa[mt] = *(const short8*)(P + (mt * 16 + row16) * 72 + kt * 32 + quad * 8);
        #pragma unroll
        for (int nt = 0; nt < 2; ++nt)
            vb[nt] = *(const short8*)(vt + (nt * 16 + row16) * 72 + kt * 32 + quad * 8);
        #pragma unroll
        for (int mt = 0; mt < 4; ++mt)
            #pragma unroll
            for (int nt = 0; nt < 2; ++nt)
                oacc[mt][nt] = __builtin_amdgcn_mfma_f32_16x16x32_bf16(pa[mt], vb[nt], oacc[mt][nt], 0, 0, 0);
    }
    #pragma unroll
    for (int mt = 0; mt < 4; ++mt)
        #pragma unroll
        for (int nt = 0; nt < 2; ++nt)
            #pragma unroll
            for (int r = 0; r < 4; ++r) {
                int row = mt * 16 + quad * 4 + r;
                if (row < Nn)
                    o[((size_t)bw * Nn + row) * Cc + hd * HD + nt * 16 + row16] = f2bf(oacc[mt][nt][r]);
            }
}

// ---------------------------------------------------------------------------
// Proj GEMM (32 rows/wave) + merge/reverse-shift scatter + residual + LN2.
// Writes x1 (fp32, token order) and m (bf16 LN2 output, token order).
// ---------------------------------------------------------------------------
__global__ __launch_bounds__(256) void proj_ln2(const short* __restrict__ o,
                                                const short* __restrict__ wt,
                                                const float* __restrict__ pb,
                                                const float* __restrict__ x,
                                                const float* __restrict__ g2,
                                                const float* __restrict__ b2,
                                                float* __restrict__ x1,
                                                short* __restrict__ m) {
    __shared__ int dest[128];
    int tid = threadIdx.x;
    int wave = tid >> 6, lane = tid & 63;
    int row16 = lane & 15, quad = lane >> 4;
    int s0 = blockIdx.x * 128;
    if (tid < 128) {
        int st = s0 + tid;
        int bimg = st / (NWw * Nn);
        int rem = st % (NWw * Nn);
        int wi = rem / Nn, n = rem % Nn;
        int wh = wi >> 3, ww = wi & 7;
        int i = n / 7, j = n % 7;
        int dr = (wh * 7 + i + SHIFT) % Hh;
        int dc = (ww * 7 + j + SHIFT) % Ww;
        dest[tid] = bimg * (Hh * Ww) + dr * Ww + dc;
    }
    __syncthreads();
    int r0w = wave * 32;
    short8 afr[2][4];
    #pragma unroll
    for (int rt = 0; rt < 2; ++rt)
        #pragma unroll
        for (int k = 0; k < 4; ++k)
            afr[rt][k] = *(const short8*)(o + ((size_t)s0 + r0w + rt * 16 + row16) * Cc + k * 32 + quad * 8);
    f32x4 acc[2][8];
    #pragma unroll
    for (int rt = 0; rt < 2; ++rt)
        #pragma unroll
        for (int n = 0; n < 8; ++n) acc[rt][n] = (f32x4)(0.f);
    #pragma unroll
    for (int k = 0; k < 4; ++k) {
        #pragma unroll
        for (int n = 0; n < 8; ++n) {
            short8 bfr = *(const short8*)(wt + (size_t)(n * 16 + row16) * Cc + k * 32 + quad * 8);
            acc[0][n] = __builtin_amdgcn_mfma_f32_16x16x32_bf16(afr[0][k], bfr, acc[0][n], 0, 0, 0);
            acc[1][n] = __builtin_amdgcn_mfma_f32_16x16x32_bf16(afr[1][k], bfr, acc[1][n], 0, 0, 0);
        }
    }
    float gv[8], bv[8], pbv[8];
    #pragma unroll
    for (int n = 0; n < 8; ++n) {
        int col = n * 16 + row16;
        gv[n] = g2[col]; bv[n] = b2[col]; pbv[n] = pb[col];
    }
    // residual add (x gathered at dest)
    #pragma unroll
    for (int rt = 0; rt < 2; ++rt)
        #pragma unroll
        for (int r = 0; r < 4; ++r) {
            int di = dest[r0w + rt * 16 + quad * 4 + r];
            #pragma unroll
            for (int n = 0; n < 8; ++n)
                acc[rt][n][r] += x[(size_t)di * Cc + n * 16 + row16] + pbv[n];
        }
    // LN2 per row + stores
    #pragma unroll
    for (int rt = 0; rt < 2; ++rt)
        #pragma unroll
        for (int r = 0; r < 4; ++r) {
            float sum = 0.f;
            #pragma unroll
            for (int n = 0; n < 8; ++n) sum += acc[rt][n][r];
            #pragma unroll
            for (int mk = 1; mk < 16; mk <<= 1) sum += __shfl_xor(sum, mk, 64);
            float mean = sum * (1.f / 128.f);
            float var = 0.f;
            #pragma unroll
            for (int n = 0; n < 8; ++n) {
                float d = acc[rt][n][r] - mean;
                var += d * d;
            }
            #pragma unroll
            for (int mk = 1; mk < 16; mk <<= 1) var += __shfl_xor(var, mk, 64);
            float inv = rsqrtf(var * (1.f / 128.f) + 1e-5f);
            int di = dest[r0w + rt * 16 + quad * 4 + r];
            #pragma unroll
            for (int n = 0; n < 8; ++n) {
                size_t idx = (size_t)di * Cc + n * 16 + row16;
                float v = acc[rt][n][r];
                x1[idx] = v;
                m[idx] = f2bf((v - mean) * inv * gv[n] + bv[n]);
            }
        }
}

// ---------------------------------------------------------------------------
// Fused MLP, 32 rows/wave, per-wave LDS H (no cross-wave barriers), fast GELU.
// ---------------------------------------------------------------------------
__global__ __launch_bounds__(256) void mlp_mfma(const short* __restrict__ m,
                                                const short* __restrict__ w1t,
                                                const float* __restrict__ b1,
                                                const short* __restrict__ w2t,
                                                const float* __restrict__ b2,
                                                const float* __restrict__ x1,
                                                float* __restrict__ out) {
    __shared__ short Hs[4][32 * 136];
    int wave = threadIdx.x >> 6, lane = threadIdx.x & 63;
    int row16 = lane & 15, quad = lane >> 4;
    size_t r0 = (size_t)blockIdx.x * 128 + wave * 32;
    short* Hw = &Hs[wave][0];
    short8 afr[2][4];
    #pragma unroll
    for (int rt = 0; rt < 2; ++rt)
        #pragma unroll
        for (int k = 0; k < 4; ++k)
            afr[rt][k] = *(const short8*)(m + (r0 + rt * 16 + row16) * Cc + k * 32 + quad * 8);
    f32x4 acc2[2][8];
    #pragma unroll
    for (int rt = 0; rt < 2; ++rt)
        #pragma unroll
        for (int n = 0; n < 8; ++n) acc2[rt][n] = (f32x4)(0.f);
    for (int ch = 0; ch < 4; ++ch) {
        f32x4 acc1[2][8];
        #pragma unroll
        for (int rt = 0; rt < 2; ++rt)
            #pragma unroll
            for (int n = 0; n < 8; ++n) acc1[rt][n] = (f32x4)(0.f);
        #pragma unroll
        for (int k = 0; k < 4; ++k) {
            #pragma unroll
            for (int n = 0; n < 8; ++n) {
                short8 bfr = *(const short8*)(w1t + (size_t)(ch * 128 + n * 16 + row16) * Cc + k * 32 + quad * 8);
                acc1[0][n] = __builtin_amdgcn_mfma_f32_16x16x32_bf16(afr[0][k], bfr, acc1[0][n], 0, 0, 0);
                acc1[1][n] = __builtin_amdgcn_mfma_f32_16x16x32_bf16(afr[1][k], bfr, acc1[1][n], 0, 0, 0);
            }
        }
        #pragma unroll
        for (int rt = 0; rt < 2; ++rt)
            #pragma unroll
            for (int n = 0; n < 8; ++n) {
                int col = n * 16 + row16;
                float bb = b1[ch * 128 + col];
                #pragma unroll
                for (int r = 0; r < 4; ++r) {
                    float hv = gelu_fast(acc1[rt][n][r] + bb);
                    Hw[(rt * 16 + quad * 4 + r) * 136 + col] = f2bf(hv);
                }
            }
        LDS_FENCE();
        #pragma unroll
        for (int k = 0; k < 4; ++k) {
            short8 a2[2];
            #pragma unroll
            for (int rt = 0; rt < 2; ++rt)
                a2[rt] = *(const short8*)(Hw + (rt * 16 + row16) * 136 + k * 32 + quad * 8);
            #pragma unroll
            for (int n = 0; n < 8; ++n) {
                short8 bfr = *(const short8*)(w2t + (size_t)(n * 16 + row16) * HID + ch * 128 + k * 32 + quad * 8);
                acc2[0][n] = __builtin_amdgcn_mfma_f32_16x16x32_bf16(a2[0], bfr, acc2[0][n], 0, 0, 0);
                acc2[1][n] = __builtin_amdgcn_mfma_f32_16x16x32_bf16(a2[1], bfr, acc2[1][n], 0, 0, 0);
            }
        }
        LDS_FENCE();
    }
    #pragma unroll
    for (int rt = 0; rt < 2; ++rt)
        #pragma unroll
        for (int n = 0; n < 8; ++n) {
            int col = n * 16 + row16;
            float bb = b2[col];
            #pragma unroll
            for (int r = 0; r < 4; ++r) {
                size_t idx = (r0 + rt * 16 + quad * 4 + r) * Cc + col;
                out[idx] = x1[idx] + bb + acc2[rt][n][r];
            }
        }
}

// ---------------------------------------------------------------------------
extern "C" void kernel_launch(void* const* d_in, const int* in_sizes, int n_in,
                              void* d_out, int out_size, void* d_ws, size_t ws_size,
                              hipStream_t stream) {
    const float* x     = (const float*)d_in[0];
    const float* n1g   = (const float*)d_in[1];
    const float* n1b   = (const float*)d_in[2];
    const float* qkvw  = (const float*)d_in[3];
    const float* qkvb  = (const float*)d_in[4];
    const float* projw = (const float*)d_in[5];
    const float* projb = (const float*)d_in[6];
    const float* rpb   = (const float*)d_in[7];
    const float* n2g   = (const float*)d_in[8];
    const float* n2b   = (const float*)d_in[9];
    const float* fc1w  = (const float*)d_in[10];
    const float* fc1b  = (const float*)d_in[11];
    const float* fc2w  = (const float*)d_in[12];
    const float* fc2b  = (const float*)d_in[13];
    float* out = (float*)d_out;

    // workspace layout (bytes):
    //   [0)           qkv bf16   77,070,336
    //   [qkv)         x1  fp32   51,380,224   (bias table lives here pre-proj)
    //   [x1)          h/m bf16   25,690,112
    //   [h)           o   bf16   25,690,112
    //   [o)           weights bf16 ~0.38 MB
    char* ws = (char*)d_ws;
    short* qkv   = (short*)ws;
    float* x1    = (float*)(ws + 77070336);
    float* table = x1;  // dead until proj_ln2 writes x1 (attn reads it first)
    short* h     = (short*)(ws + 77070336 + 51380224);
    short* m     = h;
    short* o     = (short*)(ws + 77070336 + 51380224 + 25690112);
    short* qkvwT = (short*)(ws + 77070336 + 51380224 + 2 * 25690112);
    short* projwT= qkvwT + 384 * 128;
    short* fc1wT = projwT + 128 * 128;
    short* fc2wT = fc1wT + 512 * 128;

    conv_t<<<(128 * 384 + 255) / 256, 256, 0, stream>>>(qkvw, qkvwT, 128, 384);
    conv_t<<<(128 * 128 + 255) / 256, 256, 0, stream>>>(projw, projwT, 128, 128);
    conv_t<<<(128 * 512 + 255) / 256, 256, 0, stream>>>(fc1w, fc1wT, 128, 512);
    conv_t<<<(512 * 128 + 255) / 256, 256, 0, stream>>>(fc2w, fc2wT, 512, 128);
    build_table<<<256, 256, 0, stream>>>(rpb, table);

    ln1_gather<<<TOK / 4, 256, 0, stream>>>(x, n1g, n1b, h);
    qkv_mfma<<<TOK / 128, 256, 0, stream>>>(h, qkvwT, qkvb, qkv);
    attn_mfma<<<(TOK / Nn) * HEAD / 4, 256, 0, stream>>>(qkv, table, o);
    proj_ln2<<<TOK / 128, 256, 0, stream>>>(o, projwT, projb, x, n2g, n2b, x1, m);
    mlp_mfma<<<TOK / 128, 256, 0, stream>>>(m, fc1wT, fc1b, fc2wT, fc2b, x1, out);
}